// Round 3
// baseline (815.853 us; speedup 1.0000x reference)
//
#include <hip/hip_runtime.h>
#include <cstdint>
#include <cstddef>

// ---------------------------------------------------------------------------
// Threefry-2x32, 20 rounds, key = (0, 42) — replica of JAX's
// jax.random.bernoulli(jax.random.key(42), 0.5, (N,F)) mask with the
// PARTITIONABLE threefry path (JAX default since v0.5.0):
//   per element j (row-major):  (o0,o1) = threefry2x32(key, x0=j>>32, x1=j&0xffffffff)
//   bits = o0 ^ o1 ;  keep <=> (bits >> 31) == 0
// (N*F = 51.2M < 2^32, so x0 = 0 for all elements.)
// ---------------------------------------------------------------------------
__device__ __forceinline__ uint32_t rotl32(uint32_t x, int r) {
    return (x << r) | (x >> (32 - r));
}

__device__ __forceinline__ void threefry2x32(uint32_t x0, uint32_t x1,
                                             uint32_t& o0, uint32_t& o1) {
    const uint32_t k0 = 0u;
    const uint32_t k1 = 42u;
    const uint32_t k2 = k0 ^ k1 ^ 0x1BD11BDAu;
    x0 += k0; x1 += k1;
#define TF_R4(a, b, c, d)                                         \
    x0 += x1; x1 = rotl32(x1, a); x1 ^= x0;                       \
    x0 += x1; x1 = rotl32(x1, b); x1 ^= x0;                       \
    x0 += x1; x1 = rotl32(x1, c); x1 ^= x0;                       \
    x0 += x1; x1 = rotl32(x1, d); x1 ^= x0;
    TF_R4(13, 15, 26, 6)   x0 += k1; x1 += k2 + 1u;
    TF_R4(17, 29, 16, 24)  x0 += k2; x1 += k0 + 2u;
    TF_R4(13, 15, 26, 6)   x0 += k0; x1 += k1 + 3u;
    TF_R4(17, 29, 16, 24)  x0 += k1; x1 += k2 + 4u;
    TF_R4(13, 15, 26, 6)   x0 += k2; x1 += k0 + 5u;
#undef TF_R4
    o0 = x0; o1 = x1;
}

// ---------------------------------------------------------------------------
// Kernel 1: per-edge degree accumulation: deg[row[e]] += w[e]
// ---------------------------------------------------------------------------
__global__ void k_deg(const int* __restrict__ row, const float* __restrict__ w,
                      float* __restrict__ deg, int E) {
    int e = blockIdx.x * blockDim.x + threadIdx.x;
    if (e < E) atomicAdd(&deg[row[e]], w[e]);
}

// ---------------------------------------------------------------------------
// Kernel 2: dinv[n] = rsqrt(deg[n] + 1)   (self-loop weight folded in)
// ---------------------------------------------------------------------------
__global__ void k_dinv(float* __restrict__ deg, int N) {
    int n = blockIdx.x * blockDim.x + threadIdx.x;
    if (n < N) deg[n] = rsqrtf(deg[n] + 1.0f);
}

// ---------------------------------------------------------------------------
// Kernel 3: h = dropout(x) @ W   ([N,512] @ [512,2] -> [N,2], fp32)
// One wave per node; lane l handles f in [8l, 8l+8); one threefry per element.
// ---------------------------------------------------------------------------
__global__ __launch_bounds__(256) void k_h(const float* __restrict__ x,
                                           const float* __restrict__ W,
                                           float* __restrict__ h,
                                           int N, int F) {
    const int wave = (int)((blockIdx.x * blockDim.x + threadIdx.x) >> 6);
    const int lane = threadIdx.x & 63;
    if (wave >= N) return;
    const int m = wave;
    const int f0 = lane * 8;

    const float4* xa = (const float4*)(x + (size_t)m * F + f0);
    float4 a0 = xa[0], a1 = xa[1];
    float va[8] = {a0.x, a0.y, a0.z, a0.w, a1.x, a1.y, a1.z, a1.w};

    const uint32_t jbase = (uint32_t)m * (uint32_t)F + (uint32_t)f0;
    float acc0 = 0.f, acc1 = 0.f;

#pragma unroll
    for (int t = 0; t < 8; ++t) {
        uint32_t o0, o1;
        threefry2x32(0u, jbase + (uint32_t)t, o0, o1);
        uint32_t bits = o0 ^ o1;
        // keep <=> MSB clear; kept values scaled by 1/(1-0.5) = 2
        float xv = (bits >> 31) ? 0.0f : va[t] * 2.0f;
        acc0 += xv * W[(f0 + t) * 2 + 0];
        acc1 += xv * W[(f0 + t) * 2 + 1];
    }
#pragma unroll
    for (int off = 32; off >= 1; off >>= 1) {
        acc0 += __shfl_xor(acc0, off);
        acc1 += __shfl_xor(acc1, off);
    }
    if (lane == 0) {
        h[(size_t)m * 2 + 0] = acc0;
        h[(size_t)m * 2 + 1] = acc1;
    }
}

// ---------------------------------------------------------------------------
// Kernel 4: out[n,:] = b + dinv[n]^2 * h[n,:]   (bias + self-loop term)
// ---------------------------------------------------------------------------
__global__ void k_selfinit(const float* __restrict__ h,
                           const float* __restrict__ dinv,
                           const float* __restrict__ b,
                           float* __restrict__ out, int N) {
    int n = blockIdx.x * blockDim.x + threadIdx.x;
    if (n < N) {
        float d = dinv[n];
        float s = d * d;
        float2 hv = ((const float2*)h)[n];
        float2 o;
        o.x = b[0] + s * hv.x;
        o.y = b[1] + s * hv.y;
        ((float2*)out)[n] = o;
    }
}

// ---------------------------------------------------------------------------
// Kernel 5: per-edge scatter: out[row,:] += dinv[row]*w*dinv[col] * h[col,:]
// ---------------------------------------------------------------------------
__global__ void k_edge(const int* __restrict__ row, const int* __restrict__ col,
                       const float* __restrict__ w,
                       const float* __restrict__ dinv,
                       const float* __restrict__ h,
                       float* __restrict__ out, int E) {
    int e = blockIdx.x * blockDim.x + threadIdx.x;
    if (e < E) {
        int r = row[e], c = col[e];
        float nrm = dinv[r] * w[e] * dinv[c];
        float2 hv = ((const float2*)h)[c];
        atomicAdd(&out[(size_t)r * 2 + 0], nrm * hv.x);
        atomicAdd(&out[(size_t)r * 2 + 1], nrm * hv.y);
    }
}

extern "C" void kernel_launch(void* const* d_in, const int* in_sizes, int n_in,
                              void* d_out, int out_size, void* d_ws, size_t ws_size,
                              hipStream_t stream) {
    const float* x  = (const float*)d_in[0];
    const int*   ei = (const int*)d_in[1];
    const float* ew = (const float*)d_in[2];
    const float* W  = (const float*)d_in[3];
    const float* b  = (const float*)d_in[4];
    float* out = (float*)d_out;

    const int C = in_sizes[4];            // 2
    const int F = in_sizes[3] / C;        // 512
    const int N = in_sizes[0] / F;        // 100000
    const int E = in_sizes[1] / 2;        // 3200000
    const int* row = ei;
    const int* col = ei + E;

    float* deg = (float*)d_ws;            // N floats (becomes dinv in-place)
    float* h   = deg + N;                 // N*2 floats

    hipMemsetAsync(deg, 0, (size_t)N * sizeof(float), stream);
    k_deg<<<(E + 255) / 256, 256, 0, stream>>>(row, ew, deg, E);
    k_dinv<<<(N + 255) / 256, 256, 0, stream>>>(deg, N);
    k_h<<<(N + 3) / 4, 256, 0, stream>>>(x, W, h, N, F);
    k_selfinit<<<(N + 255) / 256, 256, 0, stream>>>(h, deg, b, out, N);
    k_edge<<<(E + 255) / 256, 256, 0, stream>>>(row, col, ew, deg, h, out, E);
}